// Round 1
// 114.421 us; speedup vs baseline: 1.0596x; 1.0596x over previous
//
#include <hip/hip_runtime.h>

// Problem constants
#define B_   8
#define TE_  256
#define TD_  256
#define D_   256
#define U_   256

// Workspace layout (float offsets). ~4.2 MB.
// EeT is stored INTERLEAVED: EeT[b][u4][t][j] = exp2(2log2e*ae[b,t,4*u4+j])
// so the K24 u-loop reads one float4 (4 u-values) per lane per iteration.
#define EET_OFF   0        // (B, U/4, TE, 4)
#define ED_OFF    524288   // (B, TD, U)  Ed = exp2(2log2e * de@w_de), row-major
#define MAXMU_OFF 1048576  // (B, TD)     row max of mu'

__device__ __forceinline__ float fexp2(float x) {
#if __has_builtin(__builtin_amdgcn_exp2f)
  return __builtin_amdgcn_exp2f(x);
#else
  return exp2f(x);
#endif
}
__device__ __forceinline__ float frcp(float x) {
#if __has_builtin(__builtin_amdgcn_rcpf)
  return __builtin_amdgcn_rcpf(x);
#else
  return 1.0f / x;
#endif
}

#define LOG2E_F 1.4426950408889634f
#define TWO_LOG2E_F 2.8853900817779268f

// ---------------------------------------------------------------------------
// K1: Ed = exp2(2log2e * de@w_de) row-major; Ee -> interleaved-transposed
// EeT[b][u4][t][j] via LDS transpose epilogue. 64x64 tile, K-chunks of 32,
// double-buffered, 512 threads (4x2 microtile) for 2 waves/SIMD occupancy.
// grid (4, 32, 2) = 256 blocks.
// ---------------------------------------------------------------------------
__global__ __launch_bounds__(512) void coatt_k1_proj(
    const float* __restrict__ en, const float* __restrict__ de,
    const float* __restrict__ w_en, const float* __restrict__ w_de,
    float* __restrict__ ws) {
  const int which = blockIdx.z;  // 0: en->EeT (interleaved), 1: de->Ed (direct)
  const float* __restrict__ A = which ? de : en;     // (2048, 256)
  const float* __restrict__ W = which ? w_de : w_en; // (256, 256)
  const int rowBase = blockIdx.y * 64;   // global row in (B*T)
  const int colBase = blockIdx.x * 64;   // col in U
  __shared__ float smem[2][2][32][68];   // [A/B][buf][k][rowOrCol]
  const int tid = threadIdx.x;
  const int tx = tid & 31, ty = tid >> 5;      // compute: col0=tx*2, row0=ty*4
  const int aRow = tid >> 3, aC4 = tid & 7;    // A stage: 64 rows x 8 float4-k
  const int bK = tid >> 4, bC4 = tid & 15;     // B stage: 32 k x 16 float4-col

  // prologue: chunk 0
  float4 aR = *(const float4*)&A[(size_t)(rowBase + aRow) * D_ + aC4 * 4];
  float4 bR = *(const float4*)&W[(size_t)bK * U_ + colBase + bC4 * 4];
  {
    float v[4]; *(float4*)v = aR;
#pragma unroll
    for (int j = 0; j < 4; ++j) smem[0][0][aC4 * 4 + j][aRow] = v[j];
    *(float4*)&smem[1][0][bK][bC4 * 4] = bR;
  }
  __syncthreads();

  float acc[4][2] = {};
#define K1_COMPUTE(BUF)                                              \
  _Pragma("unroll")                                                  \
  for (int k = 0; k < 32; ++k) {                                     \
    float av[4], bv[2];                                              \
    *(float4*)av = *(const float4*)&smem[0][BUF][k][ty * 4];         \
    *(float2*)bv = *(const float2*)&smem[1][BUF][k][tx * 2];         \
    _Pragma("unroll")                                                \
    for (int i = 0; i < 4; ++i)                                      \
      _Pragma("unroll")                                              \
      for (int j = 0; j < 2; ++j)                                    \
        acc[i][j] = fmaf(av[i], bv[j], acc[i][j]);                   \
  }

  for (int kc = 0; kc < 7; ++kc) {
    const int k0 = (kc + 1) * 32;
    aR = *(const float4*)&A[(size_t)(rowBase + aRow) * D_ + k0 + aC4 * 4];
    bR = *(const float4*)&W[(size_t)(k0 + bK) * U_ + colBase + bC4 * 4];
    const int cur = kc & 1, nxt = cur ^ 1;
    K1_COMPUTE(cur)
    {
      float v[4]; *(float4*)v = aR;
#pragma unroll
      for (int j = 0; j < 4; ++j) smem[0][nxt][aC4 * 4 + j][aRow] = v[j];
      *(float4*)&smem[1][nxt][bK][bC4 * 4] = bR;
    }
    __syncthreads();
  }
  K1_COMPUTE(1)

  if (which) {
    // Ed: direct row-major float2 store
    float* __restrict__ outp = ws + ED_OFF;
#pragma unroll
    for (int i = 0; i < 4; ++i) {
      float2 o;
      o.x = fexp2(acc[i][0] * TWO_LOG2E_F);
      o.y = fexp2(acc[i][1] * TWO_LOG2E_F);
      *(float2*)&outp[(size_t)(rowBase + ty * 4 + i) * U_ + colBase + tx * 2] = o;
    }
  } else {
    // EeT interleaved: Cs[u_local][t_local] (pitch 69 -> 2-way banks), then
    // gather 4 consecutive-u values into a float4 stored at stride-4t layout
    // (fully contiguous 1KB per wave).
    __syncthreads();  // smem dead after last compute; reuse as Cs
    float* Cs = &smem[0][0][0][0];  // need 64*69 = 4416 <= 8704 floats
#pragma unroll
    for (int i = 0; i < 4; ++i)
#pragma unroll
      for (int j = 0; j < 2; ++j)
        Cs[(tx * 2 + j) * 69 + ty * 4 + i] = fexp2(acc[i][j] * TWO_LOG2E_F);
    __syncthreads();
    float* __restrict__ outp = ws + EET_OFF;
    const int b = rowBase >> 8, t0 = rowBase & 255;
    const int u4Base = colBase >> 2;
#pragma unroll
    for (int kk = 0; kk < 2; ++kk) {
      const int q = tid + 512 * kk;
      const int u4l = q >> 6, tl = q & 63;  // 16 u4-groups x 64 t
      float4 v;
      v.x = Cs[(u4l * 4 + 0) * 69 + tl];
      v.y = Cs[(u4l * 4 + 1) * 69 + tl];
      v.z = Cs[(u4l * 4 + 2) * 69 + tl];
      v.w = Cs[(u4l * 4 + 3) * 69 + tl];
      *(float4*)&outp[(size_t)((b * 64 + u4Base + u4l) * 256 + t0 + tl) * 4] = v;
    }
  }
}

// ---------------------------------------------------------------------------
// K24 (fused K2+K4): per block (b, 4 s-rows), thread t=tid.
// Phase u: mu'[s][t] = -2 * sum_u nu_u * rcp(fma(Ed[s,u], Ee[t,u], 1))
//   Ee: ONE coalesced global dwordx4 per 4 u (interleaved layout).
//   Ed/nu: wave-uniform -> s_load. Fused row-softmax -> alphas kept in LDS
//   (no global roundtrip), maxmu written for K3.
// Phase t: sum_en[s,d] = sum_t alphas[s,t]*en[t,d], alphas via LDS broadcast,
//   en coalesced (lane=d). Writes out chunks 0..2; chunk 3 (de*h_hat) is
//   written by K3 after the cross-block maxmu softmax.
// grid (64, 8) = 512 blocks.
// ---------------------------------------------------------------------------
__global__ __launch_bounds__(256) void coatt_k24(
    const float* __restrict__ en, const float* __restrict__ de,
    const float* __restrict__ nu, float* __restrict__ ws,
    float* __restrict__ out) {
  const float* __restrict__ EeT = ws + EET_OFF;
  const float* __restrict__ Ed = ws + ED_OFF;
  float* __restrict__ maxmu = ws + MAXMU_OFF;
  const int b = blockIdx.y;
  const int sBase = blockIdx.x * 4;
  const int tid = threadIdx.x;
  const int w = tid >> 6, lane = tid & 63;
  const float* __restrict__ Ee_b = EeT + (size_t)b * U_ * TE_ + tid * 4;
  const float* __restrict__ Ed_b = Ed + (size_t)(b * TD_ + sBase) * U_;

  float acc0 = 0.f, acc1 = 0.f, acc2 = 0.f, acc3 = 0.f;
#pragma unroll 4
  for (int u4 = 0; u4 < 64; ++u4) {
    const float4 nv = *(const float4*)&nu[u4 * 4];              // uniform -> SGPR
    const float4 e0 = *(const float4*)&Ed_b[0 * U_ + u4 * 4];   // uniform -> SGPR
    const float4 e1 = *(const float4*)&Ed_b[1 * U_ + u4 * 4];
    const float4 e2 = *(const float4*)&Ed_b[2 * U_ + u4 * 4];
    const float4 e3 = *(const float4*)&Ed_b[3 * U_ + u4 * 4];
    const float4 ee4 = *(const float4*)&Ee_b[u4 * 1024];        // coalesced 16B
    const float* nvp = (const float*)&nv;
    const float* eep = (const float*)&ee4;
    const float* p0 = (const float*)&e0;
    const float* p1 = (const float*)&e1;
    const float* p2 = (const float*)&e2;
    const float* p3 = (const float*)&e3;
#pragma unroll
    for (int j = 0; j < 4; ++j) {
      acc0 = fmaf(nvp[j], frcp(fmaf(p0[j], eep[j], 1.0f)), acc0);
      acc1 = fmaf(nvp[j], frcp(fmaf(p1[j], eep[j], 1.0f)), acc1);
      acc2 = fmaf(nvp[j], frcp(fmaf(p2[j], eep[j], 1.0f)), acc2);
      acc3 = fmaf(nvp[j], frcp(fmaf(p3[j], eep[j], 1.0f)), acc3);
    }
  }
  // mu' = -2*acc. Fused softmax over t (256 threads = 4 waves).
  float v[4] = {-2.f * acc0, -2.f * acc1, -2.f * acc2, -2.f * acc3};
  __shared__ float part[4][4];   // [s][wave]
  __shared__ float als[4][256];  // alphas, consumed by phase t
  float m[4];
#pragma unroll
  for (int s = 0; s < 4; ++s) {
    m[s] = v[s];
#pragma unroll
    for (int off = 32; off > 0; off >>= 1) m[s] = fmaxf(m[s], __shfl_xor(m[s], off));
    if (lane == 0) part[s][w] = m[s];
  }
  __syncthreads();
#pragma unroll
  for (int s = 0; s < 4; ++s)
    m[s] = fmaxf(fmaxf(part[s][0], part[s][1]), fmaxf(part[s][2], part[s][3]));
  __syncthreads();
  float e[4], sm[4];
#pragma unroll
  for (int s = 0; s < 4; ++s) {
    e[s] = fexp2((v[s] - m[s]) * LOG2E_F);
    sm[s] = e[s];
#pragma unroll
    for (int off = 32; off > 0; off >>= 1) sm[s] += __shfl_xor(sm[s], off);
    if (lane == 0) part[s][w] = sm[s];
  }
  __syncthreads();
#pragma unroll
  for (int s = 0; s < 4; ++s) {
    const float tot = (part[s][0] + part[s][1]) + (part[s][2] + part[s][3]);
    als[s][tid] = e[s] * frcp(tot);
  }
  if (tid == 0) {
#pragma unroll
    for (int s = 0; s < 4; ++s) maxmu[b * TD_ + sBase + s] = m[s];
  }
  __syncthreads();

  // Phase t: d = tid, alphas via LDS broadcast float4s, en coalesced.
  const int d = tid;
  const float* __restrict__ en_b = en + (size_t)b * TE_ * D_ + d;
  float sa0 = 0.f, sa1 = 0.f, sa2 = 0.f, sa3 = 0.f;
#pragma unroll 4
  for (int t4 = 0; t4 < 64; ++t4) {
    const float4 a0 = *(const float4*)&als[0][t4 * 4];  // broadcast, no conflict
    const float4 a1 = *(const float4*)&als[1][t4 * 4];
    const float4 a2 = *(const float4*)&als[2][t4 * 4];
    const float4 a3 = *(const float4*)&als[3][t4 * 4];
    float env[4];
#pragma unroll
    for (int j = 0; j < 4; ++j) env[j] = en_b[(t4 * 4 + j) * D_];  // coalesced
    const float* q0 = (const float*)&a0;
    const float* q1 = (const float*)&a1;
    const float* q2 = (const float*)&a2;
    const float* q3 = (const float*)&a3;
#pragma unroll
    for (int j = 0; j < 4; ++j) {
      sa0 = fmaf(q0[j], env[j], sa0);
      sa1 = fmaf(q1[j], env[j], sa1);
      sa2 = fmaf(q2[j], env[j], sa2);
      sa3 = fmaf(q3[j], env[j], sa3);
    }
  }
  const float se[4] = {sa0, sa1, sa2, sa3};
#pragma unroll
  for (int s = 0; s < 4; ++s) {
    const float dd = de[(size_t)(b * TD_ + sBase + s) * D_ + d];
    float* o = out + (size_t)(b * TD_ + sBase + s) * (4 * D_);
    o[d] = dd;
    o[D_ + d] = se[s];
    o[2 * D_ + d] = dd * se[s];
  }
}

// ---------------------------------------------------------------------------
// K3: max_alphas = softmax_s(maxmu[b,:]); h_hat[b,dchunk] = sum_s de*ma[s];
// then writes out chunk 3 = de * h_hat for all s at its 32 d-columns.
// grid (8 dChunks, 8 b), 256 threads.
// ---------------------------------------------------------------------------
__global__ __launch_bounds__(256) void coatt_k3_hhat(
    const float* __restrict__ de, const float* __restrict__ ws,
    float* __restrict__ out) {
  const float* __restrict__ maxmu = ws + MAXMU_OFF;
  const int b = blockIdx.y;
  const int dBase = blockIdx.x * 32;
  const int tid = threadIdx.x;
  const int w = tid >> 6, lane = tid & 63;
  __shared__ float red[8];
  __shared__ float malpha[256];
  __shared__ float acc_red[256];
  __shared__ float hh_s[32];
  const float vv = maxmu[b * TD_ + tid];
  float m = vv;
#pragma unroll
  for (int off = 32; off > 0; off >>= 1) m = fmaxf(m, __shfl_xor(m, off));
  if (lane == 0) red[w] = m;
  __syncthreads();
  m = fmaxf(fmaxf(red[0], red[1]), fmaxf(red[2], red[3]));
  const float e = fexp2((vv - m) * LOG2E_F);
  float sm = e;
#pragma unroll
  for (int off = 32; off > 0; off >>= 1) sm += __shfl_xor(sm, off);
  if (lane == 0) red[4 + w] = sm;
  __syncthreads();
  sm = (red[4] + red[5]) + (red[6] + red[7]);
  malpha[tid] = e * frcp(sm);
  __syncthreads();
  const int dl = tid & 31, sg = tid >> 5;
  float acc = 0.f;
  for (int s = sg * 32; s < sg * 32 + 32; ++s)
    acc = fmaf(de[(size_t)(b * TD_ + s) * D_ + dBase + dl], malpha[s], acc);
  acc_red[tid] = acc;
  __syncthreads();
  if (tid < 32) {
    float t = acc_red[tid];
#pragma unroll
    for (int g = 1; g < 8; ++g) t += acc_red[g * 32 + tid];
    hh_s[tid] = t;
  }
  __syncthreads();
  const float hh = hh_s[dl];
#pragma unroll 4
  for (int s = sg; s < TD_; s += 8) {
    const float dd = de[(size_t)(b * TD_ + s) * D_ + dBase + dl];
    out[(size_t)(b * TD_ + s) * (4 * D_) + 3 * D_ + dBase + dl] = dd * hh;
  }
}

extern "C" void kernel_launch(void* const* d_in, const int* in_sizes, int n_in,
                              void* d_out, int out_size, void* d_ws, size_t ws_size,
                              hipStream_t stream) {
  (void)in_sizes; (void)n_in; (void)out_size; (void)ws_size;
  const float* en   = (const float*)d_in[0];
  const float* de   = (const float*)d_in[1];
  const float* w_en = (const float*)d_in[2];
  const float* w_de = (const float*)d_in[3];
  const float* nu   = (const float*)d_in[4];
  float* out = (float*)d_out;
  float* ws  = (float*)d_ws;

  coatt_k1_proj<<<dim3(4, 32, 2), 512, 0, stream>>>(en, de, w_en, w_de, ws);
  coatt_k24<<<dim3(64, 8), 256, 0, stream>>>(en, de, nu, ws, out);
  coatt_k3_hhat<<<dim3(8, 8), 256, 0, stream>>>(de, ws, out);
}

// Round 2
// 112.661 us; speedup vs baseline: 1.0761x; 1.0156x over previous
//
#include <hip/hip_runtime.h>

// Problem constants
#define B_   8
#define TE_  256
#define TD_  256
#define D_   256
#define U_   256

// Workspace layout (float offsets). ~4.2 MB.
// EeT is stored INTERLEAVED: EeT[b][u4][t][j] = exp2(2log2e*ae[b,t,4*u4+j])
// so the K24 u-loop reads one float4 (4 u-values) per lane per iteration.
#define EET_OFF   0        // (B, U/4, TE, 4)
#define ED_OFF    524288   // (B, TD, U)  Ed = exp2(2log2e * de@w_de), row-major
#define MAXMU_OFF 1048576  // (B, TD)     row max of mu'

__device__ __forceinline__ float fexp2(float x) {
#if __has_builtin(__builtin_amdgcn_exp2f)
  return __builtin_amdgcn_exp2f(x);
#else
  return exp2f(x);
#endif
}
__device__ __forceinline__ float frcp(float x) {
#if __has_builtin(__builtin_amdgcn_rcpf)
  return __builtin_amdgcn_rcpf(x);
#else
  return 1.0f / x;
#endif
}

#define LOG2E_F 1.4426950408889634f
#define TWO_LOG2E_F 2.8853900817779268f

// ---------------------------------------------------------------------------
// K1: Ed = exp2(2log2e * de@w_de) row-major; Ee -> interleaved-transposed
// EeT[b][u4][t][j] via LDS transpose epilogue. 64x64 tile, 4x4 microtile
// (1.5 B/MAC LDS traffic), K-chunks of 32, double-buffered, 256 threads.
// grid (4, 32, 2) = 256 blocks.
// ---------------------------------------------------------------------------
__global__ __launch_bounds__(256) void coatt_k1_proj(
    const float* __restrict__ en, const float* __restrict__ de,
    const float* __restrict__ w_en, const float* __restrict__ w_de,
    float* __restrict__ ws) {
  const int which = blockIdx.z;  // 0: en->EeT (interleaved), 1: de->Ed (direct)
  const float* __restrict__ A = which ? de : en;     // (2048, 256)
  const float* __restrict__ W = which ? w_de : w_en; // (256, 256)
  const int rowBase = blockIdx.y * 64;   // global row in (B*T)
  const int colBase = blockIdx.x * 64;   // col in U
  __shared__ float smem[2][2][32][69];   // [A/B][buf][k][rowOrCol], pitch 69
  const int tid = threadIdx.x;
  const int tx = tid & 15, ty = tid >> 4;      // compute: col0=tx*4, row0=ty*4
  const int aRow0 = tid >> 3, aC4 = tid & 7;   // A stage: 32 rows x 8 f4-k (+32)
  const int bK0 = tid >> 4, bC4 = tid & 15;    // B stage: 16 k x 16 f4-col (+16)
  float4 aR[2], bR[2];

  // prologue: chunk 0
#pragma unroll
  for (int kk = 0; kk < 2; ++kk) {
    aR[kk] = *(const float4*)&A[(size_t)(rowBase + aRow0 + 32 * kk) * D_ + aC4 * 4];
    bR[kk] = *(const float4*)&W[(size_t)(bK0 + 16 * kk) * U_ + colBase + bC4 * 4];
  }
#pragma unroll
  for (int kk = 0; kk < 2; ++kk) {
    float v[4]; *(float4*)v = aR[kk];
#pragma unroll
    for (int j = 0; j < 4; ++j) smem[0][0][aC4 * 4 + j][aRow0 + 32 * kk] = v[j];
    *(float4*)&smem[1][0][bK0 + 16 * kk][bC4 * 4] = bR[kk];
  }
  __syncthreads();

  float acc[4][4] = {};
#define K1_COMPUTE(BUF)                                              \
  _Pragma("unroll")                                                  \
  for (int k = 0; k < 32; ++k) {                                     \
    float av[4], bv[4];                                              \
    *(float4*)av = *(const float4*)&smem[0][BUF][k][ty * 4];         \
    *(float4*)bv = *(const float4*)&smem[1][BUF][k][tx * 4];         \
    _Pragma("unroll")                                                \
    for (int i = 0; i < 4; ++i)                                      \
      _Pragma("unroll")                                              \
      for (int j = 0; j < 4; ++j)                                    \
        acc[i][j] = fmaf(av[i], bv[j], acc[i][j]);                   \
  }

  for (int kc = 0; kc < 7; ++kc) {
    const int k0 = (kc + 1) * 32;
#pragma unroll
    for (int kk = 0; kk < 2; ++kk) {
      aR[kk] = *(const float4*)&A[(size_t)(rowBase + aRow0 + 32 * kk) * D_ + k0 + aC4 * 4];
      bR[kk] = *(const float4*)&W[(size_t)(k0 + bK0 + 16 * kk) * U_ + colBase + bC4 * 4];
    }
    const int cur = kc & 1, nxt = cur ^ 1;
    K1_COMPUTE(cur)
#pragma unroll
    for (int kk = 0; kk < 2; ++kk) {
      float v[4]; *(float4*)v = aR[kk];
#pragma unroll
      for (int j = 0; j < 4; ++j) smem[0][nxt][aC4 * 4 + j][aRow0 + 32 * kk] = v[j];
      *(float4*)&smem[1][nxt][bK0 + 16 * kk][bC4 * 4] = bR[kk];
    }
    __syncthreads();
  }
  K1_COMPUTE(1)

  if (which) {
    // Ed: direct row-major float4 store
    float* __restrict__ outp = ws + ED_OFF;
#pragma unroll
    for (int i = 0; i < 4; ++i) {
      float4 o;
      o.x = fexp2(acc[i][0] * TWO_LOG2E_F);
      o.y = fexp2(acc[i][1] * TWO_LOG2E_F);
      o.z = fexp2(acc[i][2] * TWO_LOG2E_F);
      o.w = fexp2(acc[i][3] * TWO_LOG2E_F);
      *(float4*)&outp[(size_t)(rowBase + ty * 4 + i) * U_ + colBase + tx * 4] = o;
    }
  } else {
    // EeT interleaved: Cs[u_local][t_local] (pitch 69), then gather 4
    // consecutive-u values into a float4 at [b][u4][t][4] (contiguous stores).
    __syncthreads();  // smem dead after last compute; reuse as Cs
    float* Cs = &smem[0][0][0][0];  // need 64*69 = 4416 <= 8832 floats
#pragma unroll
    for (int i = 0; i < 4; ++i)
#pragma unroll
      for (int j = 0; j < 4; ++j)
        Cs[(tx * 4 + j) * 69 + ty * 4 + i] = fexp2(acc[i][j] * TWO_LOG2E_F);
    __syncthreads();
    float* __restrict__ outp = ws + EET_OFF;
    const int b = rowBase >> 8, t0 = rowBase & 255;
    const int u4Base = colBase >> 2;
#pragma unroll
    for (int kk = 0; kk < 4; ++kk) {
      const int q = tid + 256 * kk;
      const int u4l = q >> 6, tl = q & 63;  // 16 u4-groups x 64 t
      float4 v;
      v.x = Cs[(u4l * 4 + 0) * 69 + tl];
      v.y = Cs[(u4l * 4 + 1) * 69 + tl];
      v.z = Cs[(u4l * 4 + 2) * 69 + tl];
      v.w = Cs[(u4l * 4 + 3) * 69 + tl];
      *(float4*)&outp[(size_t)((b * 64 + u4Base + u4l) * 256 + t0 + tl) * 4] = v;
    }
  }
}

// ---------------------------------------------------------------------------
// K24 (fused K2+K4), 512 threads = 8 waves -> with 2 blocks/CU: 4 waves/SIMD.
// Wave-halves split the 4 s-rows (half 0: s0,s1; half 1: s2,s3), t = tid&255.
// Phase u: mu'[s][t] = -2 * sum_u nu_u * rcp(fma(Ed[s,u], Ee[t,u], 1))
//   Ee: one coalesced global dwordx4 per 4 u. Ed/nu: preloaded in LDS ->
//   broadcast ds_read_b128 (no per-iter scalar-cache stalls).
// Fused softmax over t -> alphas kept in LDS; maxmu written for K3.
// Phase t: halves cover disjoint t-ranges (no duplicate en reads), partial
//   sums combined via LDS. Writes out chunks 0..2; chunk 3 deferred to K3.
// grid flat 512 blocks; b = id&7 so each XCD's L2 holds only its b's panels.
// ---------------------------------------------------------------------------
__global__ __launch_bounds__(512) void coatt_k24(
    const float* __restrict__ en, const float* __restrict__ de,
    const float* __restrict__ nu, float* __restrict__ ws,
    float* __restrict__ out) {
  const float* __restrict__ EeT = ws + EET_OFF;
  const float* __restrict__ Ed = ws + ED_OFF;
  float* __restrict__ maxmu = ws + MAXMU_OFF;
  const int id = blockIdx.x;
  const int b = id & 7;             // XCD-aligned: id%8 tracks XCD assignment
  const int sBase = (id >> 3) * 4;
  const int tid = threadIdx.x;      // 0..511
  const int t = tid & 255;
  const int half = tid >> 8;        // 0/1 -> local s rows {0,1} / {2,3}
  const int w = tid >> 6, lane = tid & 63;

  __shared__ float eds[4][256];   // 4 Ed rows
  __shared__ float nus[256];
  __shared__ float als[4][256];   // alphas
  __shared__ float tp[2][4][256]; // t-phase partials [half][s][d]
  __shared__ float part[2][8];    // softmax partials [s-local-in-half][wave]

  // Preload Ed rows + nu into LDS (coalesced float2).
  {
    const float2* src = (const float2*)(Ed + (size_t)(b * TD_ + sBase) * U_);
    ((float2*)&eds[0][0])[tid] = src[tid];  // 512 float2 = 1024 floats
    if (tid < 128) ((float2*)nus)[tid] = ((const float2*)nu)[tid];
  }
  __syncthreads();

  const float* __restrict__ Ee_b = EeT + (size_t)b * (U_ * TE_) + t * 4;
  const int s0 = half * 2;
  float accA0 = 0.f, accB0 = 0.f, accA1 = 0.f, accB1 = 0.f;  // 2 chains per s
#pragma unroll 4
  for (int u4 = 0; u4 < 64; ++u4) {
    const float4 ee4 = *(const float4*)&Ee_b[u4 * 1024];        // coalesced 16B
    const float4 nv = *(const float4*)&nus[u4 * 4];             // LDS broadcast
    const float4 d0 = *(const float4*)&eds[s0][u4 * 4];
    const float4 d1 = *(const float4*)&eds[s0 + 1][u4 * 4];
    const float* eep = (const float*)&ee4;
    const float* nvp = (const float*)&nv;
    const float* p0 = (const float*)&d0;
    const float* p1 = (const float*)&d1;
#pragma unroll
    for (int j = 0; j < 4; ++j) {
      const float r0 = frcp(fmaf(p0[j], eep[j], 1.0f));
      const float r1 = frcp(fmaf(p1[j], eep[j], 1.0f));
      if (j & 1) {
        accB0 = fmaf(nvp[j], r0, accB0);
        accB1 = fmaf(nvp[j], r1, accB1);
      } else {
        accA0 = fmaf(nvp[j], r0, accA0);
        accA1 = fmaf(nvp[j], r1, accA1);
      }
    }
  }
  float v0 = -2.f * (accA0 + accB0);
  float v1 = -2.f * (accA1 + accB1);

  // Softmax over t for the 2 local s-rows; each covered by the half's 4 waves.
  float m0 = v0, m1 = v1;
#pragma unroll
  for (int off = 32; off > 0; off >>= 1) {
    m0 = fmaxf(m0, __shfl_xor(m0, off));
    m1 = fmaxf(m1, __shfl_xor(m1, off));
  }
  if (lane == 0) { part[0][w] = m0; part[1][w] = m1; }
  __syncthreads();
  const int wb = half * 4;
  m0 = fmaxf(fmaxf(part[0][wb], part[0][wb + 1]), fmaxf(part[0][wb + 2], part[0][wb + 3]));
  m1 = fmaxf(fmaxf(part[1][wb], part[1][wb + 1]), fmaxf(part[1][wb + 2], part[1][wb + 3]));
  __syncthreads();
  const float e0 = fexp2((v0 - m0) * LOG2E_F);
  const float e1 = fexp2((v1 - m1) * LOG2E_F);
  float sm0 = e0, sm1 = e1;
#pragma unroll
  for (int off = 32; off > 0; off >>= 1) {
    sm0 += __shfl_xor(sm0, off);
    sm1 += __shfl_xor(sm1, off);
  }
  if (lane == 0) { part[0][w] = sm0; part[1][w] = sm1; }
  __syncthreads();
  const float tot0 = (part[0][wb] + part[0][wb + 1]) + (part[0][wb + 2] + part[0][wb + 3]);
  const float tot1 = (part[1][wb] + part[1][wb + 1]) + (part[1][wb + 2] + part[1][wb + 3]);
  als[s0][t] = e0 * frcp(tot0);
  als[s0 + 1][t] = e1 * frcp(tot1);
  if (t == 0) {
    maxmu[b * TD_ + sBase + s0] = m0;
    maxmu[b * TD_ + sBase + s0 + 1] = m1;
  }
  __syncthreads();

  // Phase t: d = t; halves cover disjoint t-ranges for ALL 4 s-rows.
  const int d = t;
  const int tBeg = half * 128;
  const float* __restrict__ en_b = en + (size_t)b * TE_ * D_ + d;
  float sa0 = 0.f, sa1 = 0.f, sa2 = 0.f, sa3 = 0.f;
#pragma unroll 4
  for (int t4 = 0; t4 < 32; ++t4) {
    const int tt = tBeg + t4 * 4;
    const float4 a0 = *(const float4*)&als[0][tt];  // LDS broadcast
    const float4 a1 = *(const float4*)&als[1][tt];
    const float4 a2 = *(const float4*)&als[2][tt];
    const float4 a3 = *(const float4*)&als[3][tt];
    float env[4];
#pragma unroll
    for (int j = 0; j < 4; ++j) env[j] = en_b[(size_t)(tt + j) * D_];  // coalesced
    const float* q0 = (const float*)&a0;
    const float* q1 = (const float*)&a1;
    const float* q2 = (const float*)&a2;
    const float* q3 = (const float*)&a3;
#pragma unroll
    for (int j = 0; j < 4; ++j) {
      sa0 = fmaf(q0[j], env[j], sa0);
      sa1 = fmaf(q1[j], env[j], sa1);
      sa2 = fmaf(q2[j], env[j], sa2);
      sa3 = fmaf(q3[j], env[j], sa3);
    }
  }
  tp[half][0][d] = sa0;
  tp[half][1][d] = sa1;
  tp[half][2][d] = sa2;
  tp[half][3][d] = sa3;
  __syncthreads();
#pragma unroll
  for (int k = 0; k < 2; ++k) {
    const int sl = s0 + k;
    const float se = tp[0][sl][d] + tp[1][sl][d];
    const int s = sBase + sl;
    const float dd = de[(size_t)(b * TD_ + s) * D_ + d];
    float* o = out + (size_t)(b * TD_ + s) * (4 * D_);
    o[d] = dd;
    o[D_ + d] = se;
    o[2 * D_ + d] = dd * se;
  }
}

// ---------------------------------------------------------------------------
// K3: max_alphas = softmax_s(maxmu[b,:]); h_hat[b,dchunk] = sum_s de*ma[s];
// then writes out chunk 3 = de * h_hat for all s at its 32 d-columns.
// grid (8 dChunks, 8 b), 256 threads.
// ---------------------------------------------------------------------------
__global__ __launch_bounds__(256) void coatt_k3_hhat(
    const float* __restrict__ de, const float* __restrict__ ws,
    float* __restrict__ out) {
  const float* __restrict__ maxmu = ws + MAXMU_OFF;
  const int b = blockIdx.y;
  const int dBase = blockIdx.x * 32;
  const int tid = threadIdx.x;
  const int w = tid >> 6, lane = tid & 63;
  __shared__ float red[8];
  __shared__ float malpha[256];
  __shared__ float acc_red[256];
  __shared__ float hh_s[32];
  const float vv = maxmu[b * TD_ + tid];
  float m = vv;
#pragma unroll
  for (int off = 32; off > 0; off >>= 1) m = fmaxf(m, __shfl_xor(m, off));
  if (lane == 0) red[w] = m;
  __syncthreads();
  m = fmaxf(fmaxf(red[0], red[1]), fmaxf(red[2], red[3]));
  const float e = fexp2((vv - m) * LOG2E_F);
  float sm = e;
#pragma unroll
  for (int off = 32; off > 0; off >>= 1) sm += __shfl_xor(sm, off);
  if (lane == 0) red[4 + w] = sm;
  __syncthreads();
  sm = (red[4] + red[5]) + (red[6] + red[7]);
  malpha[tid] = e * frcp(sm);
  __syncthreads();
  const int dl = tid & 31, sg = tid >> 5;
  float acc = 0.f;
  for (int s = sg * 32; s < sg * 32 + 32; ++s)
    acc = fmaf(de[(size_t)(b * TD_ + s) * D_ + dBase + dl], malpha[s], acc);
  acc_red[tid] = acc;
  __syncthreads();
  if (tid < 32) {
    float tsum = acc_red[tid];
#pragma unroll
    for (int g = 1; g < 8; ++g) tsum += acc_red[g * 32 + tid];
    hh_s[tid] = tsum;
  }
  __syncthreads();
  const float hh = hh_s[dl];
#pragma unroll 4
  for (int s = sg; s < TD_; s += 8) {
    const float dd = de[(size_t)(b * TD_ + s) * D_ + dBase + dl];
    out[(size_t)(b * TD_ + s) * (4 * D_) + 3 * D_ + dBase + dl] = dd * hh;
  }
}

extern "C" void kernel_launch(void* const* d_in, const int* in_sizes, int n_in,
                              void* d_out, int out_size, void* d_ws, size_t ws_size,
                              hipStream_t stream) {
  (void)in_sizes; (void)n_in; (void)out_size; (void)ws_size;
  const float* en   = (const float*)d_in[0];
  const float* de   = (const float*)d_in[1];
  const float* w_en = (const float*)d_in[2];
  const float* w_de = (const float*)d_in[3];
  const float* nu   = (const float*)d_in[4];
  float* out = (float*)d_out;
  float* ws  = (float*)d_ws;

  coatt_k1_proj<<<dim3(4, 32, 2), 256, 0, stream>>>(en, de, w_en, w_de, ws);
  coatt_k24<<<dim3(512), 512, 0, stream>>>(en, de, nu, ws, out);
  coatt_k3_hhat<<<dim3(8, 8), 256, 0, stream>>>(de, ws, out);
}